// Round 3
// baseline (953.307 us; speedup 1.0000x reference)
//
#include <hip/hip_runtime.h>

#define N_AUTHOR 100000
#define N_FOS    30000
#define N_INST   8000
#define N_PAPER  200000

typedef __attribute__((ext_vector_type(8))) short short8v;
typedef __attribute__((ext_vector_type(4))) float float4v;

__device__ __forceinline__ unsigned short f2bf(float f) {
  unsigned u = __float_as_uint(f);
  u = u + 0x7fffu + ((u >> 16) & 1u);
  return (unsigned short)(u >> 16);
}

// ---------------- workspace layout (bytes) ----------------
#define O_CNT    0
#define O_OFFS   3352000
#define O_CURSOR 6704000
#define O_BTOT   10056000
#define O_CSR    10060096
#define O_WT     23260096
#define NCNT     838000

struct RelTab { const int* src; const int* dst; int E; int base; };
struct Rels { RelTab r[7]; };
struct WPtrs { const float* w[11]; };

// transpose + bf16-convert weights (W[k][n] -> WT[n][k] bf16) + zero cnt
__global__ void conv_w(WPtrs P, unsigned short* __restrict__ wt,
                       int* __restrict__ cnt) {
  int gtid = blockIdx.x * 256 + threadIdx.x;
  if (gtid < 11 * 16384) {
    int mat = gtid >> 14, rem = gtid & 16383;
    int k = rem >> 7, n = rem & 127;
    float v = P.w[mat][rem];
    wt[mat * 16384 + n * 128 + k] = f2bf(v);
  }
  for (int i = gtid; i < NCNT; i += 704 * 256) cnt[i] = 0;
}

__global__ void count_k(Rels R, int* __restrict__ cnt) {
  int gsz = gridDim.x * blockDim.x;
  int gtid = blockIdx.x * blockDim.x + threadIdx.x;
  for (int rr = 0; rr < 7; ++rr) {
    const int* dst = R.r[rr].dst;
    int E = R.r[rr].E, base = R.r[rr].base;
    for (int e = gtid; e < E; e += gsz) atomicAdd(&cnt[base + dst[e]], 1);
  }
}

__global__ void scan1(const int* __restrict__ cnt, int* __restrict__ offs,
                      int* __restrict__ btot, int n) {
  __shared__ int sh[256];
  int tid = threadIdx.x;
  int base = blockIdx.x * 2048 + tid * 8;
  int v[8]; int s = 0;
  #pragma unroll
  for (int i = 0; i < 8; ++i) { v[i] = (base + i < n) ? cnt[base + i] : 0; s += v[i]; }
  sh[tid] = s; __syncthreads();
  for (int off = 1; off < 256; off <<= 1) {
    int t = (tid >= off) ? sh[tid - off] : 0;
    __syncthreads();
    sh[tid] += t;
    __syncthreads();
  }
  int excl = sh[tid] - s;
  if (tid == 255) btot[blockIdx.x] = sh[255];
  int run = excl;
  #pragma unroll
  for (int i = 0; i < 8; ++i) { if (base + i < n) offs[base + i] = run; run += v[i]; }
}

__global__ void scan2(int* __restrict__ btot, int nb) {
  __shared__ int sh[512];
  int tid = threadIdx.x;
  int v = (tid < nb) ? btot[tid] : 0;
  sh[tid] = v; __syncthreads();
  for (int off = 1; off < 512; off <<= 1) {
    int t = (tid >= off) ? sh[tid - off] : 0;
    __syncthreads();
    sh[tid] += t;
    __syncthreads();
  }
  if (tid < nb) btot[tid] = sh[tid] - v;  // exclusive
}

__global__ void scan3(int* __restrict__ offs, int* __restrict__ cursor,
                      const int* __restrict__ btot, int n) {
  int gsz = gridDim.x * blockDim.x;
  for (int idx = blockIdx.x * blockDim.x + threadIdx.x; idx < n; idx += gsz) {
    int b = idx >> 11;
    int v = offs[idx] + btot[b];
    offs[idx] = v;
    cursor[idx] = v;
  }
}

__global__ void fill_k(Rels R, int* __restrict__ cursor, int* __restrict__ csr) {
  int gsz = gridDim.x * blockDim.x;
  int gtid = blockIdx.x * blockDim.x + threadIdx.x;
  for (int rr = 0; rr < 7; ++rr) {
    const int* src = R.r[rr].src;
    const int* dst = R.r[rr].dst;
    int E = R.r[rr].E, base = R.r[rr].base;
    for (int e = gtid; e < E; e += gsz) {
      int p = atomicAdd(&cursor[base + dst[e]], 1);
      csr[p] = src[e];
    }
  }
}

struct GemmSrc { const float* x; const unsigned short* wt; int cntBase; };
struct TypeArgs {
  GemmSrc s[4];
  int nsrc;
  int bstart;
  int n;
  const float* bias;
  float* out;
};
struct AllArgs {
  TypeArgs t[4];
  const int* offs;
  const int* cnt;
  const int* csr;
};

#define LD4(p) (*(const float4v*)(p))

// One block = 64 output rows x 128 cols of one node type.
__global__ __launch_bounds__(256, 5) void rgcn_gemm(AllArgs A) {
  __shared__ unsigned short a_lds[64 * 128];
  const int tid = threadIdx.x;
  const int wv = tid >> 6, lane = tid & 63;

  int bid = blockIdx.x;
  int ty = (bid >= A.t[3].bstart) ? 3 : (bid >= A.t[2].bstart) ? 2
         : (bid >= A.t[1].bstart) ? 1 : 0;
  const TypeArgs& T = A.t[ty];
  const int rb = (bid - T.bstart) * 64;
  const int n = T.n;

  float4v acc[8];
  #pragma unroll
  for (int i = 0; i < 8; ++i) acc[i] = (float4v)0.0f;

  for (int kb = 0; kb < T.nsrc; ++kb) {
    const GemmSrc S = T.s[kb];
    if (S.cntBase < 0) {
      // root: direct rows fp32 -> bf16. 256 threads x 4 chunks of 8 floats.
      #pragma unroll
      for (int i = 0; i < 4; ++i) {
        int c = tid + i * 256;
        int r = c >> 4, cc = (c & 15) * 8;
        int g = rb + r;
        short8v hv;
        if (g < n) {
          float4v v0 = LD4(S.x + (size_t)g * 128 + cc);
          float4v v1 = LD4(S.x + (size_t)g * 128 + cc + 4);
          hv[0] = (short)f2bf(v0[0]); hv[1] = (short)f2bf(v0[1]);
          hv[2] = (short)f2bf(v0[2]); hv[3] = (short)f2bf(v0[3]);
          hv[4] = (short)f2bf(v1[0]); hv[5] = (short)f2bf(v1[1]);
          hv[6] = (short)f2bf(v1[2]); hv[7] = (short)f2bf(v1[3]);
        } else {
          hv = (short8v)0;
        }
        int byte = r * 256 + cc * 2; byte ^= (r & 7) << 4;
        *(short8v*)((char*)a_lds + byte) = hv;
      }
    } else {
      // relation: 8 lanes per row, 32 rows in flight, 2 rounds.
      const int p = (tid & 7) * 16;      // first float of this lane's slice
      int stA[2], dgA[2];
      #pragma unroll
      for (int rd = 0; rd < 2; ++rd) {
        int r = rd * 32 + (tid >> 3);
        int g = rb + r;
        int gc = (g < n) ? g : 0;
        int gd = S.cntBase + gc;
        stA[rd] = A.offs[gd];
        dgA[rd] = (g < n) ? A.cnt[gd] : 0;
      }
      #pragma unroll
      for (int rd = 0; rd < 2; ++rd) {
        int r = rd * 32 + (tid >> 3);
        int st = stA[rd], deg = dgA[rd];
        float4v a0 = (float4v)0.f, a1 = (float4v)0.f,
                a2 = (float4v)0.f, a3 = (float4v)0.f;
        int j = 0;
        for (; j + 4 <= deg; j += 4) {
          int i0 = A.csr[st + j],     i1 = A.csr[st + j + 1];
          int i2 = A.csr[st + j + 2], i3 = A.csr[st + j + 3];
          const float* q0 = S.x + (size_t)i0 * 128 + p;
          const float* q1 = S.x + (size_t)i1 * 128 + p;
          float4v u0 = LD4(q0), u1 = LD4(q0 + 4), u2 = LD4(q0 + 8), u3 = LD4(q0 + 12);
          float4v v0 = LD4(q1), v1 = LD4(q1 + 4), v2 = LD4(q1 + 8), v3 = LD4(q1 + 12);
          a0 += u0 + v0; a1 += u1 + v1; a2 += u2 + v2; a3 += u3 + v3;
          const float* q2 = S.x + (size_t)i2 * 128 + p;
          const float* q3 = S.x + (size_t)i3 * 128 + p;
          float4v w0 = LD4(q2), w1 = LD4(q2 + 4), w2 = LD4(q2 + 8), w3 = LD4(q2 + 12);
          float4v z0 = LD4(q3), z1 = LD4(q3 + 4), z2 = LD4(q3 + 8), z3 = LD4(q3 + 12);
          a0 += w0 + z0; a1 += w1 + z1; a2 += w2 + z2; a3 += w3 + z3;
        }
        if (j < deg) {
          // masked 1-3 edge tail, branch-free loads (clamped indices)
          int j1 = (j + 1 < deg) ? j + 1 : j;
          int j2 = (j + 2 < deg) ? j + 2 : j;
          float m1 = (j + 1 < deg) ? 1.f : 0.f;
          float m2 = (j + 2 < deg) ? 1.f : 0.f;
          int i0 = A.csr[st + j], i1 = A.csr[st + j1], i2 = A.csr[st + j2];
          const float* q0 = S.x + (size_t)i0 * 128 + p;
          const float* q1 = S.x + (size_t)i1 * 128 + p;
          const float* q2 = S.x + (size_t)i2 * 128 + p;
          float4v u0 = LD4(q0), u1 = LD4(q0 + 4), u2 = LD4(q0 + 8), u3 = LD4(q0 + 12);
          float4v v0 = LD4(q1), v1 = LD4(q1 + 4), v2 = LD4(q1 + 8), v3 = LD4(q1 + 12);
          a0 += u0 + m1 * v0; a1 += u1 + m1 * v1;
          a2 += u2 + m1 * v2; a3 += u3 + m1 * v3;
          float4v w0 = LD4(q2), w1 = LD4(q2 + 4), w2 = LD4(q2 + 8), w3 = LD4(q2 + 12);
          a0 += m2 * w0; a1 += m2 * w1; a2 += m2 * w2; a3 += m2 * w3;
        }
        float sc = 1.0f / (float)((deg > 0) ? deg : 1);
        a0 *= sc; a1 *= sc; a2 *= sc; a3 *= sc;
        short8v h0, h1;
        h0[0] = (short)f2bf(a0[0]); h0[1] = (short)f2bf(a0[1]);
        h0[2] = (short)f2bf(a0[2]); h0[3] = (short)f2bf(a0[3]);
        h0[4] = (short)f2bf(a1[0]); h0[5] = (short)f2bf(a1[1]);
        h0[6] = (short)f2bf(a1[2]); h0[7] = (short)f2bf(a1[3]);
        h1[0] = (short)f2bf(a2[0]); h1[1] = (short)f2bf(a2[1]);
        h1[2] = (short)f2bf(a2[2]); h1[3] = (short)f2bf(a2[3]);
        h1[4] = (short)f2bf(a3[0]); h1[5] = (short)f2bf(a3[1]);
        h1[6] = (short)f2bf(a3[2]); h1[7] = (short)f2bf(a3[3]);
        int b0 = (r * 256 + p * 2) ^ ((r & 7) << 4);
        int b1 = (r * 256 + p * 2 + 16) ^ ((r & 7) << 4);
        *(short8v*)((char*)a_lds + b0) = h0;
        *(short8v*)((char*)a_lds + b1) = h1;
      }
    }
    __syncthreads();
    // ---- A fragments from LDS ----
    short8v af[4];
    #pragma unroll
    for (int ks = 0; ks < 4; ++ks) {
      int r = wv * 16 + (lane & 15);
      int ch = ks * 4 + (lane >> 4);
      int byte = r * 256 + ch * 16; byte ^= (r & 7) << 4;
      af[ks] = *(const short8v*)((const char*)a_lds + byte);
    }
    // ---- B fragments straight from global (L1-hot), then MFMA ----
    const unsigned short* wbase = S.wt + (size_t)(lane & 15) * 128
                                + (size_t)(lane >> 4) * 8;
    #pragma unroll
    for (int ct = 0; ct < 8; ++ct) {
      short8v bfr[4];
      #pragma unroll
      for (int ks = 0; ks < 4; ++ks)
        bfr[ks] = *(const short8v*)(wbase + (size_t)ct * 16 * 128 + ks * 32);
      #pragma unroll
      for (int ks = 0; ks < 4; ++ks)
        acc[ct] = __builtin_amdgcn_mfma_f32_16x16x32_bf16(af[ks], bfr[ks], acc[ct], 0, 0, 0);
    }
    __syncthreads();
  }
  // ---- epilogue ----
  #pragma unroll
  for (int ct = 0; ct < 8; ++ct) {
    #pragma unroll
    for (int i = 0; i < 4; ++i) {
      int row = wv * 16 + (lane >> 4) * 4 + i;
      int g = rb + row;
      if (g < n) {
        int col = ct * 16 + (lane & 15);
        T.out[(size_t)g * 128 + col] = acc[ct][i] + T.bias[col];
      }
    }
  }
}

extern "C" void kernel_launch(void* const* d_in, const int* in_sizes, int n_in,
                              void* d_out, int out_size, void* d_ws, size_t ws_size,
                              hipStream_t stream) {
  const float* x_author = (const float*)d_in[0];
  const float* x_fos    = (const float*)d_in[1];
  const float* x_inst   = (const float*)d_in[2];
  const float* x_paper  = (const float*)d_in[3];

  Rels R;
  const int E[7]  = {150000, 150000, 500000, 500000, 1000000, 500000, 500000};
  const int ND[7] = {N_INST, N_AUTHOR, N_PAPER, N_AUTHOR, N_PAPER, N_FOS, N_PAPER};
  int base = 0;
  for (int r = 0; r < 7; ++r) {
    R.r[r].src = (const int*)d_in[4 + 2 * r];
    R.r[r].dst = (const int*)d_in[5 + 2 * r];
    R.r[r].E = E[r];
    R.r[r].base = base;
    base += ND[r];
  }

  char* ws = (char*)d_ws;
  int* cnt    = (int*)(ws + O_CNT);
  int* offs   = (int*)(ws + O_OFFS);
  int* cursor = (int*)(ws + O_CURSOR);
  int* btot   = (int*)(ws + O_BTOT);
  int* csr    = (int*)(ws + O_CSR);
  unsigned short* wt = (unsigned short*)(ws + O_WT);

  WPtrs WP;
  WP.w[0] = (const float*)d_in[18];
  WP.w[1] = (const float*)d_in[20];
  WP.w[2] = (const float*)d_in[22];
  WP.w[3] = (const float*)d_in[24];
  for (int r = 0; r < 7; ++r) WP.w[4 + r] = (const float*)d_in[26 + r];

  conv_w<<<704, 256, 0, stream>>>(WP, wt, cnt);
  count_k<<<1024, 256, 0, stream>>>(R, cnt);
  scan1<<<410, 256, 0, stream>>>(cnt, offs, btot, NCNT);
  scan2<<<1, 512, 0, stream>>>(btot, 410);
  scan3<<<1024, 256, 0, stream>>>(offs, cursor, btot, NCNT);
  fill_k<<<1024, 256, 0, stream>>>(R, cursor, csr);

  float* out = (float*)d_out;
  const int B_AFF = 0, B_ITA = 8000, B_WRITES = 108000, B_PTA = 308000,
            B_CITES = 408000, B_TOPIC = 608000, B_FTP = 638000;

  AllArgs A;
  A.offs = offs; A.cnt = cnt; A.csr = csr;
  for (int t = 0; t < 4; ++t)
    for (int i = 0; i < 4; ++i) A.t[t].s[i] = GemmSrc{nullptr, nullptr, 0};

  const int NB_AUTHOR = (N_AUTHOR + 63) / 64;
  const int NB_FOS    = (N_FOS + 63) / 64;
  const int NB_INST   = (N_INST + 63) / 64;
  const int NB_PAPER  = (N_PAPER + 63) / 64;

  A.t[0].s[0] = GemmSrc{x_author, wt + 0 * 16384, -1};
  A.t[0].s[1] = GemmSrc{x_inst,   wt + 5 * 16384, B_ITA};
  A.t[0].s[2] = GemmSrc{x_paper,  wt + 7 * 16384, B_PTA};
  A.t[0].nsrc = 3; A.t[0].bstart = 0; A.t[0].n = N_AUTHOR;
  A.t[0].bias = (const float*)d_in[19]; A.t[0].out = out;

  A.t[1].s[0] = GemmSrc{x_fos,   wt + 1 * 16384, -1};
  A.t[1].s[1] = GemmSrc{x_paper, wt + 9 * 16384, B_TOPIC};
  A.t[1].nsrc = 2; A.t[1].bstart = NB_AUTHOR; A.t[1].n = N_FOS;
  A.t[1].bias = (const float*)d_in[21]; A.t[1].out = out + (size_t)100000 * 128;

  A.t[2].s[0] = GemmSrc{x_inst,   wt + 2 * 16384, -1};
  A.t[2].s[1] = GemmSrc{x_author, wt + 4 * 16384, B_AFF};
  A.t[2].nsrc = 2; A.t[2].bstart = NB_AUTHOR + NB_FOS; A.t[2].n = N_INST;
  A.t[2].bias = (const float*)d_in[23]; A.t[2].out = out + (size_t)130000 * 128;

  A.t[3].s[0] = GemmSrc{x_paper,  wt + 3 * 16384, -1};
  A.t[3].s[1] = GemmSrc{x_author, wt + 6 * 16384, B_WRITES};
  A.t[3].s[2] = GemmSrc{x_paper,  wt + 8 * 16384, B_CITES};
  A.t[3].s[3] = GemmSrc{x_fos,    wt + 10 * 16384, B_FTP};
  A.t[3].nsrc = 4; A.t[3].bstart = NB_AUTHOR + NB_FOS + NB_INST; A.t[3].n = N_PAPER;
  A.t[3].bias = (const float*)d_in[25]; A.t[3].out = out + (size_t)138000 * 128;

  const int NB_TOTAL = NB_AUTHOR + NB_FOS + NB_INST + NB_PAPER;
  rgcn_gemm<<<NB_TOTAL, 256, 0, stream>>>(A);
}

// Round 4
// 900.280 us; speedup vs baseline: 1.0589x; 1.0589x over previous
//
#include <hip/hip_runtime.h>

#define N_AUTHOR 100000
#define N_FOS    30000
#define N_INST   8000
#define N_PAPER  200000

typedef __attribute__((ext_vector_type(8))) short short8v;
typedef __attribute__((ext_vector_type(4))) float float4v;

__device__ __forceinline__ unsigned short f2bf(float f) {
  unsigned u = __float_as_uint(f);
  u = u + 0x7fffu + ((u >> 16) & 1u);
  return (unsigned short)(u >> 16);
}
#define BF2F(s) __uint_as_float(((unsigned)(unsigned short)(s)) << 16)

__device__ __forceinline__ void acc8(float4v& x, float4v& y, short8v h) {
  x[0] += BF2F(h[0]); x[1] += BF2F(h[1]); x[2] += BF2F(h[2]); x[3] += BF2F(h[3]);
  y[0] += BF2F(h[4]); y[1] += BF2F(h[5]); y[2] += BF2F(h[6]); y[3] += BF2F(h[7]);
}

// ---------------- workspace layout (bytes) ----------------
#define O_CNT    0
#define O_OFFS   3352000
#define O_CURSOR 6704000
#define O_BTOT   10056000
#define O_CSR    10060096
#define O_WT     23260096
#define XB_AUTHOR 23620544
#define XB_FOS    49220544
#define XB_INST   56900544
#define XB_PAPER  58948544
#define WS_NEED_BF 110148544ULL
#define NCNT     838000

struct RelTab { const int* src; const int* dst; int E; int base; };
struct Rels { RelTab r[7]; };
struct WPtrs { const float* w[11]; };
struct XCvt { const float* x; unsigned short* xb; int n8; };

// merged prep: W transpose+bf16, zero cnt, x fp32->bf16 (if doX)
__global__ void prep(WPtrs P, unsigned short* __restrict__ wt,
                     int* __restrict__ cnt, XCvt x0, XCvt x1, XCvt x2, XCvt x3,
                     int doX) {
  int gsz = gridDim.x * blockDim.x;
  int gtid = blockIdx.x * blockDim.x + threadIdx.x;
  for (int i = gtid; i < 11 * 16384; i += gsz) {
    int mat = i >> 14, rem = i & 16383;
    int k = rem >> 7, n = rem & 127;
    wt[mat * 16384 + n * 128 + k] = f2bf(P.w[mat][rem]);
  }
  for (int i = gtid; i < NCNT; i += gsz) cnt[i] = 0;
  if (doX) {
    XCvt xc[4] = {x0, x1, x2, x3};
    #pragma unroll
    for (int a = 0; a < 4; ++a) {
      const float* xp = xc[a].x;
      short8v* xbp = (short8v*)xc[a].xb;
      int n8 = xc[a].n8;
      for (int i = gtid; i < n8; i += gsz) {
        float4v v0 = *(const float4v*)(xp + (size_t)i * 8);
        float4v v1 = *(const float4v*)(xp + (size_t)i * 8 + 4);
        short8v h;
        h[0] = (short)f2bf(v0[0]); h[1] = (short)f2bf(v0[1]);
        h[2] = (short)f2bf(v0[2]); h[3] = (short)f2bf(v0[3]);
        h[4] = (short)f2bf(v1[0]); h[5] = (short)f2bf(v1[1]);
        h[6] = (short)f2bf(v1[2]); h[7] = (short)f2bf(v1[3]);
        xbp[i] = h;
      }
    }
  }
}

__global__ void count_k(Rels R, int* __restrict__ cnt) {
  int gsz = gridDim.x * blockDim.x;
  int gtid = blockIdx.x * blockDim.x + threadIdx.x;
  for (int rr = 0; rr < 7; ++rr) {
    const int* dst = R.r[rr].dst;
    int E = R.r[rr].E, base = R.r[rr].base;
    for (int e = gtid; e < E; e += gsz) atomicAdd(&cnt[base + dst[e]], 1);
  }
}

__global__ void scan1(const int* __restrict__ cnt, int* __restrict__ offs,
                      int* __restrict__ btot, int n) {
  __shared__ int sh[256];
  int tid = threadIdx.x;
  int base = blockIdx.x * 2048 + tid * 8;
  int v[8]; int s = 0;
  #pragma unroll
  for (int i = 0; i < 8; ++i) { v[i] = (base + i < n) ? cnt[base + i] : 0; s += v[i]; }
  sh[tid] = s; __syncthreads();
  for (int off = 1; off < 256; off <<= 1) {
    int t = (tid >= off) ? sh[tid - off] : 0;
    __syncthreads();
    sh[tid] += t;
    __syncthreads();
  }
  int excl = sh[tid] - s;
  if (tid == 255) btot[blockIdx.x] = sh[255];
  int run = excl;
  #pragma unroll
  for (int i = 0; i < 8; ++i) { if (base + i < n) offs[base + i] = run; run += v[i]; }
}

// merged scan2+scan3: every block redundantly scans btot (<=512), then applies
__global__ void scan23(int* __restrict__ offs, int* __restrict__ cursor,
                       const int* __restrict__ btot, int nb, int n) {
  __shared__ int sh[512];
  int tid = threadIdx.x;   // 512 threads
  int v = (tid < nb) ? btot[tid] : 0;
  sh[tid] = v; __syncthreads();
  for (int off = 1; off < 512; off <<= 1) {
    int t = (tid >= off) ? sh[tid - off] : 0;
    __syncthreads();
    sh[tid] += t;
    __syncthreads();
  }
  int excl = sh[tid] - v;
  __syncthreads();
  sh[tid] = excl;
  __syncthreads();
  int gsz = gridDim.x * 512;
  for (int idx = blockIdx.x * 512 + tid; idx < n; idx += gsz) {
    int val = offs[idx] + sh[idx >> 11];
    offs[idx] = val;
    cursor[idx] = val;
  }
}

__global__ void fill_k(Rels R, int* __restrict__ cursor, int* __restrict__ csr) {
  int gsz = gridDim.x * blockDim.x;
  int gtid = blockIdx.x * blockDim.x + threadIdx.x;
  for (int rr = 0; rr < 7; ++rr) {
    const int* src = R.r[rr].src;
    const int* dst = R.r[rr].dst;
    int E = R.r[rr].E, base = R.r[rr].base;
    for (int e = gtid; e < E; e += gsz) {
      int p = atomicAdd(&cursor[base + dst[e]], 1);
      csr[p] = src[e];
    }
  }
}

struct GemmSrc { const float* x; const unsigned short* xb;
                 const unsigned short* wt; int cntBase; };
struct TypeArgs {
  GemmSrc s[4];
  int nsrc;
  int bstart;
  int n;
  const float* bias;
  float* out;
};
struct AllArgs {
  TypeArgs t[4];
  const int* offs;
  const int* cnt;
  const int* csr;
};

#define LD4(p) (*(const float4v*)(p))

template <int BF>
__global__ __launch_bounds__(256, 4) void rgcn_gemm(AllArgs A) {
  __shared__ unsigned short a_lds[64 * 128];
  const int tid = threadIdx.x;
  const int wv = tid >> 6, lane = tid & 63;

  int bid = blockIdx.x;
  int ty = (bid >= A.t[3].bstart) ? 3 : (bid >= A.t[2].bstart) ? 2
         : (bid >= A.t[1].bstart) ? 1 : 0;
  const TypeArgs& T = A.t[ty];
  const int rb = (bid - T.bstart) * 64;
  const int n = T.n;

  float4v acc[8];
  #pragma unroll
  for (int i = 0; i < 8; ++i) acc[i] = (float4v)0.0f;

  for (int kb = 0; kb < T.nsrc; ++kb) {
    const GemmSrc S = T.s[kb];
    if (S.cntBase < 0) {
      // -------- root staging --------
      if (BF) {
        // direct bf16 copy: thread t -> row t>>2, 64B chunk (t&3)
        int r = tid >> 2, cb = (tid & 3) * 64;
        int g = rb + r;
        const short8v* p = (const short8v*)(S.xb + (size_t)g * 128 + (cb >> 1));
        #pragma unroll
        for (int k = 0; k < 4; ++k) {
          short8v h = (g < n) ? p[k] : (short8v)0;
          int byte = (r * 256 + cb + k * 16) ^ ((r & 7) << 4);
          *(short8v*)((char*)a_lds + byte) = h;
        }
      } else {
        #pragma unroll
        for (int i = 0; i < 4; ++i) {
          int c = tid + i * 256;
          int r = c >> 4, cc = (c & 15) * 8;
          int g = rb + r;
          short8v hv;
          if (g < n) {
            float4v v0 = LD4(S.x + (size_t)g * 128 + cc);
            float4v v1 = LD4(S.x + (size_t)g * 128 + cc + 4);
            hv[0] = (short)f2bf(v0[0]); hv[1] = (short)f2bf(v0[1]);
            hv[2] = (short)f2bf(v0[2]); hv[3] = (short)f2bf(v0[3]);
            hv[4] = (short)f2bf(v1[0]); hv[5] = (short)f2bf(v1[1]);
            hv[6] = (short)f2bf(v1[2]); hv[7] = (short)f2bf(v1[3]);
          } else hv = (short8v)0;
          int byte = r * 256 + cc * 2; byte ^= (r & 7) << 4;
          *(short8v*)((char*)a_lds + byte) = hv;
        }
      }
    } else if (BF) {
      // -------- bf16 gather: 4 lanes/row, all 64 rows in flight --------
      const int r = tid >> 2;
      const int c0 = (tid & 3) * 32;            // bf16 elem offset (64B)
      int g = rb + r;
      int gd = S.cntBase + ((g < n) ? g : 0);
      int st = A.offs[gd];
      int deg = (g < n) ? A.cnt[gd] : 0;
      float4v a0 = (float4v)0.f, a1 = (float4v)0.f, a2 = (float4v)0.f,
              a3 = (float4v)0.f, a4 = (float4v)0.f, a5 = (float4v)0.f,
              a6 = (float4v)0.f, a7 = (float4v)0.f;
      int j = 0;
      for (; j + 2 <= deg; j += 2) {
        int i0 = A.csr[st + j], i1 = A.csr[st + j + 1];
        const short8v* p0 = (const short8v*)(S.xb + (size_t)i0 * 128 + c0);
        const short8v* p1 = (const short8v*)(S.xb + (size_t)i1 * 128 + c0);
        short8v h0 = p0[0], h1 = p0[1], h2 = p0[2], h3 = p0[3];
        short8v k0 = p1[0], k1 = p1[1], k2 = p1[2], k3 = p1[3];
        acc8(a0, a1, h0); acc8(a2, a3, h1); acc8(a4, a5, h2); acc8(a6, a7, h3);
        acc8(a0, a1, k0); acc8(a2, a3, k1); acc8(a4, a5, k2); acc8(a6, a7, k3);
      }
      if (j < deg) {
        int i0 = A.csr[st + j];
        const short8v* p0 = (const short8v*)(S.xb + (size_t)i0 * 128 + c0);
        short8v h0 = p0[0], h1 = p0[1], h2 = p0[2], h3 = p0[3];
        acc8(a0, a1, h0); acc8(a2, a3, h1); acc8(a4, a5, h2); acc8(a6, a7, h3);
      }
      float sc = 1.0f / (float)((deg > 0) ? deg : 1);
      a0 *= sc; a1 *= sc; a2 *= sc; a3 *= sc;
      a4 *= sc; a5 *= sc; a6 *= sc; a7 *= sc;
      short8v o0, o1, o2, o3;
      o0[0] = (short)f2bf(a0[0]); o0[1] = (short)f2bf(a0[1]);
      o0[2] = (short)f2bf(a0[2]); o0[3] = (short)f2bf(a0[3]);
      o0[4] = (short)f2bf(a1[0]); o0[5] = (short)f2bf(a1[1]);
      o0[6] = (short)f2bf(a1[2]); o0[7] = (short)f2bf(a1[3]);
      o1[0] = (short)f2bf(a2[0]); o1[1] = (short)f2bf(a2[1]);
      o1[2] = (short)f2bf(a2[2]); o1[3] = (short)f2bf(a2[3]);
      o1[4] = (short)f2bf(a3[0]); o1[5] = (short)f2bf(a3[1]);
      o1[6] = (short)f2bf(a3[2]); o1[7] = (short)f2bf(a3[3]);
      o2[0] = (short)f2bf(a4[0]); o2[1] = (short)f2bf(a4[1]);
      o2[2] = (short)f2bf(a4[2]); o2[3] = (short)f2bf(a4[3]);
      o2[4] = (short)f2bf(a5[0]); o2[5] = (short)f2bf(a5[1]);
      o2[6] = (short)f2bf(a5[2]); o2[7] = (short)f2bf(a5[3]);
      o3[0] = (short)f2bf(a6[0]); o3[1] = (short)f2bf(a6[1]);
      o3[2] = (short)f2bf(a6[2]); o3[3] = (short)f2bf(a6[3]);
      o3[4] = (short)f2bf(a7[0]); o3[5] = (short)f2bf(a7[1]);
      o3[6] = (short)f2bf(a7[2]); o3[7] = (short)f2bf(a7[3]);
      int bbase = r * 256 + c0 * 2;
      int sw = (r & 7) << 4;
      *(short8v*)((char*)a_lds + ((bbase) ^ sw)) = o0;
      *(short8v*)((char*)a_lds + ((bbase + 16) ^ sw)) = o1;
      *(short8v*)((char*)a_lds + ((bbase + 32) ^ sw)) = o2;
      *(short8v*)((char*)a_lds + ((bbase + 48) ^ sw)) = o3;
    } else {
      // -------- fp32 gather fallback (R2 design) --------
      const int q = lane >> 4;
      const int c0 = (lane & 15) * 8;
      int stA[4], dgA[4];
      #pragma unroll
      for (int rd = 0; rd < 4; ++rd) {
        int r = wv * 16 + rd * 4 + q;
        int g = rb + r;
        int gc = (g < n) ? g : 0;
        int gd = S.cntBase + gc;
        stA[rd] = A.offs[gd];
        dgA[rd] = (g < n) ? A.cnt[gd] : 0;
      }
      #pragma unroll
      for (int rd = 0; rd < 4; ++rd) {
        int r = wv * 16 + rd * 4 + q;
        int st = stA[rd], deg = dgA[rd];
        float a0 = 0.f, a1 = 0.f, a2 = 0.f, a3 = 0.f;
        float a4 = 0.f, a5 = 0.f, a6 = 0.f, a7 = 0.f;
        int j = 0;
        for (; j + 2 <= deg; j += 2) {
          int s0 = A.csr[st + j], s1 = A.csr[st + j + 1];
          const float* p0 = S.x + (size_t)s0 * 128 + c0;
          const float* p1 = S.x + (size_t)s1 * 128 + c0;
          float4v u0 = LD4(p0), u1 = LD4(p0 + 4);
          float4v v0 = LD4(p1), v1 = LD4(p1 + 4);
          a0 += u0[0] + v0[0]; a1 += u0[1] + v0[1];
          a2 += u0[2] + v0[2]; a3 += u0[3] + v0[3];
          a4 += u1[0] + v1[0]; a5 += u1[1] + v1[1];
          a6 += u1[2] + v1[2]; a7 += u1[3] + v1[3];
        }
        if (j < deg) {
          int s0 = A.csr[st + j];
          const float* p0 = S.x + (size_t)s0 * 128 + c0;
          float4v u0 = LD4(p0), u1 = LD4(p0 + 4);
          a0 += u0[0]; a1 += u0[1]; a2 += u0[2]; a3 += u0[3];
          a4 += u1[0]; a5 += u1[1]; a6 += u1[2]; a7 += u1[3];
        }
        float sc = 1.0f / (float)((deg > 0) ? deg : 1);
        short8v hv;
        hv[0] = (short)f2bf(a0 * sc); hv[1] = (short)f2bf(a1 * sc);
        hv[2] = (short)f2bf(a2 * sc); hv[3] = (short)f2bf(a3 * sc);
        hv[4] = (short)f2bf(a4 * sc); hv[5] = (short)f2bf(a5 * sc);
        hv[6] = (short)f2bf(a6 * sc); hv[7] = (short)f2bf(a7 * sc);
        int byte = r * 256 + c0 * 2; byte ^= (r & 7) << 4;
        *(short8v*)((char*)a_lds + byte) = hv;
      }
    }
    __syncthreads();
    // ---- A fragments from LDS ----
    short8v af[4];
    #pragma unroll
    for (int ks = 0; ks < 4; ++ks) {
      int r = wv * 16 + (lane & 15);
      int ch = ks * 4 + (lane >> 4);
      int byte = r * 256 + ch * 16; byte ^= (r & 7) << 4;
      af[ks] = *(const short8v*)((const char*)a_lds + byte);
    }
    // ---- B fragments straight from global (L1-hot), then MFMA ----
    const unsigned short* wbase = S.wt + (size_t)(lane & 15) * 128
                                + (size_t)(lane >> 4) * 8;
    #pragma unroll
    for (int ct = 0; ct < 8; ++ct) {
      short8v bfr[4];
      #pragma unroll
      for (int ks = 0; ks < 4; ++ks)
        bfr[ks] = *(const short8v*)(wbase + (size_t)ct * 16 * 128 + ks * 32);
      #pragma unroll
      for (int ks = 0; ks < 4; ++ks)
        acc[ct] = __builtin_amdgcn_mfma_f32_16x16x32_bf16(af[ks], bfr[ks], acc[ct], 0, 0, 0);
    }
    __syncthreads();
  }
  // ---- epilogue ----
  #pragma unroll
  for (int ct = 0; ct < 8; ++ct) {
    #pragma unroll
    for (int i = 0; i < 4; ++i) {
      int row = wv * 16 + (lane >> 4) * 4 + i;
      int g = rb + row;
      if (g < n) {
        int col = ct * 16 + (lane & 15);
        T.out[(size_t)g * 128 + col] = acc[ct][i] + T.bias[col];
      }
    }
  }
}

extern "C" void kernel_launch(void* const* d_in, const int* in_sizes, int n_in,
                              void* d_out, int out_size, void* d_ws, size_t ws_size,
                              hipStream_t stream) {
  const float* x_author = (const float*)d_in[0];
  const float* x_fos    = (const float*)d_in[1];
  const float* x_inst   = (const float*)d_in[2];
  const float* x_paper  = (const float*)d_in[3];

  Rels R;
  const int E[7]  = {150000, 150000, 500000, 500000, 1000000, 500000, 500000};
  const int ND[7] = {N_INST, N_AUTHOR, N_PAPER, N_AUTHOR, N_PAPER, N_FOS, N_PAPER};
  int base = 0;
  for (int r = 0; r < 7; ++r) {
    R.r[r].src = (const int*)d_in[4 + 2 * r];
    R.r[r].dst = (const int*)d_in[5 + 2 * r];
    R.r[r].E = E[r];
    R.r[r].base = base;
    base += ND[r];
  }

  char* ws = (char*)d_ws;
  int* cnt    = (int*)(ws + O_CNT);
  int* offs   = (int*)(ws + O_OFFS);
  int* cursor = (int*)(ws + O_CURSOR);
  int* btot   = (int*)(ws + O_BTOT);
  int* csr    = (int*)(ws + O_CSR);
  unsigned short* wt = (unsigned short*)(ws + O_WT);
  unsigned short* xbA = (unsigned short*)(ws + XB_AUTHOR);
  unsigned short* xbF = (unsigned short*)(ws + XB_FOS);
  unsigned short* xbI = (unsigned short*)(ws + XB_INST);
  unsigned short* xbP = (unsigned short*)(ws + XB_PAPER);

  const int useBF = (ws_size >= WS_NEED_BF) ? 1 : 0;

  WPtrs WP;
  WP.w[0] = (const float*)d_in[18];
  WP.w[1] = (const float*)d_in[20];
  WP.w[2] = (const float*)d_in[22];
  WP.w[3] = (const float*)d_in[24];
  for (int r = 0; r < 7; ++r) WP.w[4 + r] = (const float*)d_in[26 + r];

  XCvt xcA = {x_author, xbA, N_AUTHOR * 16};
  XCvt xcF = {x_fos,    xbF, N_FOS * 16};
  XCvt xcI = {x_inst,   xbI, N_INST * 16};
  XCvt xcP = {x_paper,  xbP, N_PAPER * 16};

  prep<<<2048, 256, 0, stream>>>(WP, wt, cnt, xcA, xcF, xcI, xcP, useBF);
  count_k<<<1024, 256, 0, stream>>>(R, cnt);
  scan1<<<410, 256, 0, stream>>>(cnt, offs, btot, NCNT);
  scan23<<<1024, 512, 0, stream>>>(offs, cursor, btot, 410, NCNT);
  fill_k<<<1024, 256, 0, stream>>>(R, cursor, csr);

  float* out = (float*)d_out;
  const int B_AFF = 0, B_ITA = 8000, B_WRITES = 108000, B_PTA = 308000,
            B_CITES = 408000, B_TOPIC = 608000, B_FTP = 638000;

  AllArgs A;
  A.offs = offs; A.cnt = cnt; A.csr = csr;
  for (int t = 0; t < 4; ++t)
    for (int i = 0; i < 4; ++i) A.t[t].s[i] = GemmSrc{nullptr, nullptr, nullptr, 0};

  const int NB_AUTHOR = (N_AUTHOR + 63) / 64;
  const int NB_FOS    = (N_FOS + 63) / 64;
  const int NB_INST   = (N_INST + 63) / 64;
  const int NB_PAPER  = (N_PAPER + 63) / 64;

  A.t[0].s[0] = GemmSrc{x_author, xbA, wt + 0 * 16384, -1};
  A.t[0].s[1] = GemmSrc{x_inst,   xbI, wt + 5 * 16384, B_ITA};
  A.t[0].s[2] = GemmSrc{x_paper,  xbP, wt + 7 * 16384, B_PTA};
  A.t[0].nsrc = 3; A.t[0].bstart = 0; A.t[0].n = N_AUTHOR;
  A.t[0].bias = (const float*)d_in[19]; A.t[0].out = out;

  A.t[1].s[0] = GemmSrc{x_fos,   xbF, wt + 1 * 16384, -1};
  A.t[1].s[1] = GemmSrc{x_paper, xbP, wt + 9 * 16384, B_TOPIC};
  A.t[1].nsrc = 2; A.t[1].bstart = NB_AUTHOR; A.t[1].n = N_FOS;
  A.t[1].bias = (const float*)d_in[21]; A.t[1].out = out + (size_t)100000 * 128;

  A.t[2].s[0] = GemmSrc{x_inst,   xbI, wt + 2 * 16384, -1};
  A.t[2].s[1] = GemmSrc{x_author, xbA, wt + 4 * 16384, B_AFF};
  A.t[2].nsrc = 2; A.t[2].bstart = NB_AUTHOR + NB_FOS; A.t[2].n = N_INST;
  A.t[2].bias = (const float*)d_in[23]; A.t[2].out = out + (size_t)130000 * 128;

  A.t[3].s[0] = GemmSrc{x_paper,  xbP, wt + 3 * 16384, -1};
  A.t[3].s[1] = GemmSrc{x_author, xbA, wt + 6 * 16384, B_WRITES};
  A.t[3].s[2] = GemmSrc{x_paper,  xbP, wt + 8 * 16384, B_CITES};
  A.t[3].s[3] = GemmSrc{x_fos,    xbF, wt + 10 * 16384, B_FTP};
  A.t[3].nsrc = 4; A.t[3].bstart = NB_AUTHOR + NB_FOS + NB_INST; A.t[3].n = N_PAPER;
  A.t[3].bias = (const float*)d_in[25]; A.t[3].out = out + (size_t)138000 * 128;

  const int NB_TOTAL = NB_AUTHOR + NB_FOS + NB_INST + NB_PAPER;
  if (useBF)
    rgcn_gemm<1><<<NB_TOTAL, 256, 0, stream>>>(A);
  else
    rgcn_gemm<0><<<NB_TOTAL, 256, 0, stream>>>(A);
}